// Round 18
// baseline (153.575 us; speedup 1.0000x reference)
//
#include <hip/hip_runtime.h>
#include <hip/hip_bf16.h>

// GCN 2-layer: N=100000 nodes, E=1600000 edges, 64 -> 64(relu) -> 33.
// out = [pos (N*32) | mass (N*1)], float32.
//
// ht1[i] = bf16( (x@W1)[i] * dinv[i] )   (scaled table, single rounding)
// gcn[i] = dinv_i * ( sum_e ht1[src] + ht1[i] ) + b
//
// R18: merged split||gemm1 kept (overlap win) but gemm1 emits f32 xw;
// a ~6us streaming k_scale applies dinv after bin2 -> gathers revert to the
// EXACT R13 bodies (best measured: 46.7us gather1 @36 VGPR/57% occ; R17's
// per-edge dinv fold cost +4.6us and +8 shuffles/batch). TILE=2048 shrinks
// merged smem 23.5KB -> 16KB.

constexpr int NN = 100000;
constexpr int NE = 1600000;

constexpr int BSHIFT = 9;                               // 512 nodes per bucket
constexpr int NBUCK = (NN + (1 << BSHIFT) - 1) >> BSHIFT;   // 196
constexpr int TILE = 2048;                              // edges per split tile
constexpr int NTILE = (NE + TILE - 1) / TILE;           // 782
constexpr int GEMM1CH = (NN + 255) / 256;               // 391
constexpr int CAP = 16384;                              // bucket capacity

// ---------------- bf16 helpers ----------------

__device__ inline float bflo(unsigned w) { union { unsigned u; float f; } c; c.u = w << 16; return c.f; }
__device__ inline float bfhi(unsigned w) { union { unsigned u; float f; } c; c.u = w & 0xffff0000u; return c.f; }
__device__ inline unsigned f2bf_bits(float f) {
    __hip_bfloat16 h = __float2bfloat16(f);
    unsigned short u; __builtin_memcpy(&u, &h, 2); return (unsigned)u;
}
__device__ inline unsigned pack2(float a, float b) { return f2bf_bits(a) | (f2bf_bits(b) << 16); }

// ---------------- init: zero gcur ----------------

__global__ void k_zero(int* __restrict__ g) {
    int t = threadIdx.x;
    if (t < NBUCK) g[t] = 0;
}

// ---------------- merged split || gemm1 (no inter-block dependency) ----------------
// split path smem: lcnt[256] lpre[256] gadj[200] buf[2048] bb[2048] = 13088 B
// gemm path smem: W1 tile 16384 B.

__global__ __launch_bounds__(256, 1) void k_split_gemm(const int* __restrict__ src,
                                                       const int* __restrict__ dst,
                                                       int* __restrict__ gcur,
                                                       unsigned* __restrict__ pairs,
                                                       const float* __restrict__ x,
                                                       const float* __restrict__ W1,
                                                       float* __restrict__ xw) {
    __shared__ __align__(16) char smem[16384];
    int tid = threadIdx.x;

    if (blockIdx.x < NTILE) {
        // ---- split tile ----
        int* lcnt = (int*)smem;
        int* lpre = lcnt + 256;
        int* gadj = lpre + 256;
        unsigned* buf = (unsigned*)(gadj + 200);
        unsigned char* bb = (unsigned char*)(buf + TILE);
        int base = blockIdx.x * TILE;

        lcnt[tid] = 0;
        __syncthreads();

        unsigned pk[8]; short bk[8]; short lp[8];
        #pragma unroll
        for (int k = 0; k < 8; ++k) {
            int e = base + k * 256 + tid;
            bk[k] = -1;
            if (e < NE) {
                int s = src[e], d = dst[e];
                int b = d >> BSHIFT;
                pk[k] = (unsigned)s | ((unsigned)(d & ((1 << BSHIFT) - 1)) << 17);
                bk[k] = (short)b;
                lp[k] = (short)atomicAdd(&lcnt[b], 1);
            }
        }
        __syncthreads();

        lpre[tid] = lcnt[tid];
        __syncthreads();
        for (int off = 1; off < 256; off <<= 1) {
            int v = (tid >= off) ? lpre[tid - off] : 0;
            __syncthreads();
            lpre[tid] += v;
            __syncthreads();
        }
        int total = lpre[255];

        if (tid < NBUCK) {
            int ex = lpre[tid] - lcnt[tid];
            gadj[tid] = tid * CAP + atomicAdd(&gcur[tid], lcnt[tid]) - ex;
        }
        __syncthreads();

        #pragma unroll
        for (int k = 0; k < 8; ++k) {
            if (bk[k] >= 0) {
                int b = bk[k];
                int i = (lpre[b] - lcnt[b]) + lp[k];
                buf[i] = pk[k];
                bb[i] = (unsigned char)b;
            }
        }
        __syncthreads();

        for (int i = tid; i < total; i += 256) {
            pairs[gadj[bb[i]] + i] = buf[i];
        }
    } else {
        // ---- gemm1 chunk: xw = x @ W1 (f32, unscaled) ----
        float* w = (float*)smem;
        for (int t = tid; t < 64 * 64; t += 256) w[t] = W1[t];
        __syncthreads();

        int i = (blockIdx.x - NTILE) * 256 + tid;
        if (i >= NN) return;

        float acc[64];
        #pragma unroll
        for (int f = 0; f < 64; ++f) acc[f] = 0.f;

        const float4* xp = reinterpret_cast<const float4*>(x + (size_t)i * 64);
        #pragma unroll
        for (int kc = 0; kc < 4; ++kc) {
            float4 c0 = xp[4 * kc + 0], c1 = xp[4 * kc + 1];
            float4 c2 = xp[4 * kc + 2], c3 = xp[4 * kc + 3];
            float xs[16] = {c0.x, c0.y, c0.z, c0.w, c1.x, c1.y, c1.z, c1.w,
                            c2.x, c2.y, c2.z, c2.w, c3.x, c3.y, c3.z, c3.w};
            #pragma unroll
            for (int kk = 0; kk < 16; ++kk) {
                float xk = xs[kk];
                const float4* wr = reinterpret_cast<const float4*>(w + (16 * kc + kk) * 64);
                #pragma unroll
                for (int f4 = 0; f4 < 16; ++f4) {
                    float4 wv = wr[f4];
                    acc[4 * f4 + 0] += xk * wv.x;
                    acc[4 * f4 + 1] += xk * wv.y;
                    acc[4 * f4 + 2] += xk * wv.z;
                    acc[4 * f4 + 3] += xk * wv.w;
                }
            }
        }

        float4* hp = reinterpret_cast<float4*>(xw + (size_t)i * 64);
        #pragma unroll
        for (int q = 0; q < 16; ++q) {
            float4 v;
            v.x = acc[4 * q + 0]; v.y = acc[4 * q + 1];
            v.z = acc[4 * q + 2]; v.w = acc[4 * q + 3];
            hp[q] = v;
        }
    }
}

// ---------------- pass 2: block-per-bucket; emits csr (padded), rs, re, dinv ----------------

__global__ __launch_bounds__(256) void k_bin2(const unsigned* __restrict__ pairs,
                                              const int* __restrict__ gcur,
                                              int* __restrict__ csr,
                                              int* __restrict__ rs,
                                              int* __restrict__ re,
                                              float* __restrict__ dinv) {
    int b = blockIdx.x;
    int lo = b << BSHIFT;
    int nn = min(1 << BSHIFT, NN - lo);
    int t = threadIdx.x;
    int beg = b * CAP;
    int endd = beg + gcur[b];

    __shared__ int lcnt[1 << BSHIFT];
    __shared__ int loff[1 << BSHIFT];
    __shared__ int wsum[256];

    for (int i = t; i < (1 << BSHIFT); i += 256) lcnt[i] = 0;
    __syncthreads();
    for (int idx = beg + t; idx < endd; idx += 256)
        atomicAdd(&lcnt[pairs[idx] >> 17], 1);
    __syncthreads();

    int v0 = lcnt[2 * t], v1 = lcnt[2 * t + 1];
    int s = v0 + v1;
    wsum[t] = s; __syncthreads();
    for (int off = 1; off < 256; off <<= 1) {
        int a = (t >= off) ? wsum[t - off] : 0;
        __syncthreads();
        wsum[t] += a;
        __syncthreads();
    }
    int ex = wsum[t] - s;
    loff[2 * t] = ex; loff[2 * t + 1] = ex + v0;
    __syncthreads();

    for (int i = t; i < nn; i += 256) {
        int st = beg + loff[i];
        rs[lo + i] = st;
        re[lo + i] = st + lcnt[i];
        dinv[lo + i] = rsqrtf((float)lcnt[i] + 1.0f);
    }
    __syncthreads();
    for (int i = t; i < (1 << BSHIFT); i += 256) lcnt[i] = 0;  // reuse as cursors
    __syncthreads();

    for (int idx = beg + t; idx < endd; idx += 256) {
        unsigned v = pairs[idx];
        int dl = (int)(v >> 17);
        int p = atomicAdd(&lcnt[dl], 1);
        csr[beg + loff[dl] + p] = (int)(v & 0x1FFFFu);
    }
}

// ---------------- scale: ht1 = bf16(xw * dinv)  (streaming, ~6us) ----------------

__global__ __launch_bounds__(256) void k_scale(const float* __restrict__ xw,
                                               const float* __restrict__ dinv,
                                               unsigned short* __restrict__ ht1) {
    int t = blockIdx.x * 256 + threadIdx.x;   // NN*8 threads, 8 floats each
    int i = t >> 3, seg = t & 7;
    float di = dinv[i];
    const float4* xp = reinterpret_cast<const float4*>(xw + (size_t)i * 64 + seg * 8);
    float4 a = xp[0], b = xp[1];
    uint4 v;
    v.x = pack2(a.x * di, a.y * di);
    v.y = pack2(a.z * di, a.w * di);
    v.z = pack2(b.x * di, b.y * di);
    v.w = pack2(b.z * di, b.w * di);
    *reinterpret_cast<uint4*>(ht1 + (size_t)i * 64 + seg * 8) = v;
}

// ---------------- gather1 + relu + fused gemm2 (LDS-staged) -> htp, htm ----------------
// grid = NN*8/256 = 3125 exact; 8 lanes/node; 32 nodes/block. (exact R13 body)

__global__ __launch_bounds__(256) void k_gather1(const unsigned short* __restrict__ ht,
                                                 const int* __restrict__ rs,
                                                 const int* __restrict__ re,
                                                 const int* __restrict__ csr,
                                                 const float* __restrict__ dinv,
                                                 const float* __restrict__ b1,
                                                 const float* __restrict__ W2,
                                                 unsigned short* __restrict__ htp,
                                                 float* __restrict__ htm) {
    __shared__ float w2s[64 * 36];     // W2 padded to stride 36
    __shared__ float hs[32 * 68];      // 32 h rows, stride 68 (bank-spread)

    for (int t = threadIdx.x; t < 64 * 36; t += 256) {
        int k = t / 36, c = t - k * 36;
        w2s[t] = (c < 33) ? W2[k * 33 + c] : 0.f;
    }

    int wid = (blockIdx.x * 256 + threadIdx.x) >> 3;
    int g = threadIdx.x >> 3;          // group (node slot) in block: 0..31
    int l = threadIdx.x & 7;           // lane in group: feats 8l..8l+7
    int beg = rs[wid], end = re[wid];

    float av[8];
    #pragma unroll
    for (int k = 0; k < 8; ++k) av[k] = 0.f;

    for (int j0 = beg; j0 < end; j0 += 8) {
        int jj = j0 + l;
        int sv = csr[min(jj, end - 1)];
        uint4 rows[8];
        #pragma unroll
        for (int e = 0; e < 8; ++e) {
            int s = __shfl(sv, e, 8);
            rows[e] = *reinterpret_cast<const uint4*>(ht + (size_t)s * 64 + 8 * l);
        }
        #pragma unroll
        for (int e = 0; e < 8; ++e) {
            float msk = (j0 + e < end) ? 1.f : 0.f;
            uint4 w = rows[e];
            av[0] += msk * bflo(w.x); av[1] += msk * bfhi(w.x);
            av[2] += msk * bflo(w.y); av[3] += msk * bfhi(w.y);
            av[4] += msk * bflo(w.z); av[5] += msk * bfhi(w.z);
            av[6] += msk * bflo(w.w); av[7] += msk * bfhi(w.w);
        }
    }

    // self term + relu epilogue -> h row staged to LDS
    uint4 sw = *reinterpret_cast<const uint4*>(ht + (size_t)wid * 64 + 8 * l);
    av[0] += bflo(sw.x); av[1] += bfhi(sw.x); av[2] += bflo(sw.y); av[3] += bfhi(sw.y);
    av[4] += bflo(sw.z); av[5] += bfhi(sw.z); av[6] += bflo(sw.w); av[7] += bfhi(sw.w);

    float di = dinv[wid];
    const float4* bp = reinterpret_cast<const float4*>(b1 + 8 * l);
    float4 bA = bp[0], bB = bp[1];
    float4 vA, vB;
    vA.x = fmaxf(di * av[0] + bA.x, 0.f); vA.y = fmaxf(di * av[1] + bA.y, 0.f);
    vA.z = fmaxf(di * av[2] + bA.z, 0.f); vA.w = fmaxf(di * av[3] + bA.w, 0.f);
    vB.x = fmaxf(di * av[4] + bB.x, 0.f); vB.y = fmaxf(di * av[5] + bB.y, 0.f);
    vB.z = fmaxf(di * av[6] + bB.z, 0.f); vB.w = fmaxf(di * av[7] + bB.w, 0.f);
    float* hp = hs + g * 68 + 8 * l;
    *reinterpret_cast<float4*>(hp)     = vA;
    *reinterpret_cast<float4*>(hp + 4) = vB;
    __syncthreads();

    // fused gemm2: thread computes its node's cols 4l..4l+3 (+ col 32 broadcast)
    float acc0 = 0.f, acc1 = 0.f, acc2 = 0.f, acc3 = 0.f, accm = 0.f;
    const float* hrow = hs + g * 68;
    #pragma unroll 8
    for (int k = 0; k < 64; ++k) {
        float hv = hrow[k];
        const float* wr = w2s + k * 36 + 4 * l;
        acc0 += hv * wr[0];
        acc1 += hv * wr[1];
        acc2 += hv * wr[2];
        acc3 += hv * wr[3];
        accm += hv * w2s[k * 36 + 32];   // wave-uniform broadcast
    }
    uint2 pv;
    pv.x = pack2(acc0 * di, acc1 * di);
    pv.y = pack2(acc2 * di, acc3 * di);
    *reinterpret_cast<uint2*>(htp + (size_t)wid * 32 + 4 * l) = pv;
    if (l == 0) htm[wid] = accm * di;
}

// ---------------- layer 2 gather: 8 lanes/node, lane owns 4 cols; mass 3-shfl ----------------

__global__ __launch_bounds__(256) void k_gather2(const unsigned short* __restrict__ htp,
                                                 const float* __restrict__ htm,
                                                 const int* __restrict__ rs,
                                                 const int* __restrict__ re,
                                                 const int* __restrict__ csr,
                                                 const float* __restrict__ dinv,
                                                 const float* __restrict__ b2,
                                                 float* __restrict__ out) {
    int wid = (blockIdx.x * 256 + threadIdx.x) >> 3;
    int l = threadIdx.x & 7;           // lane in group: cols 4l..4l+3
    int beg = rs[wid], end = re[wid];

    float a0 = 0.f, a1 = 0.f, a2 = 0.f, a3 = 0.f, m = 0.f;
    for (int j0 = beg; j0 < end; j0 += 8) {
        int jj = j0 + l;
        int sv = csr[min(jj, end - 1)];
        if (jj < end) m += htm[sv];    // lane's own edge's mass
        uint2 rows[8];
        #pragma unroll
        for (int e = 0; e < 8; ++e) {
            int s = __shfl(sv, e, 8);
            rows[e] = *reinterpret_cast<const uint2*>(htp + (size_t)s * 32 + 4 * l);
        }
        #pragma unroll
        for (int e = 0; e < 8; ++e) {
            float msk = (j0 + e < end) ? 1.f : 0.f;
            uint2 w = rows[e];
            a0 += msk * bflo(w.x); a1 += msk * bfhi(w.x);
            a2 += msk * bflo(w.y); a3 += msk * bfhi(w.y);
        }
    }

    // mass reduce across the 8-lane group only
    m += __shfl_xor(m, 1); m += __shfl_xor(m, 2); m += __shfl_xor(m, 4);

    float di = dinv[wid];
    uint2 sw = *reinterpret_cast<const uint2*>(htp + (size_t)wid * 32 + 4 * l);
    a0 += bflo(sw.x); a1 += bfhi(sw.x); a2 += bflo(sw.y); a3 += bfhi(sw.y);
    const float4* bp = reinterpret_cast<const float4*>(b2 + 4 * l);
    float4 bv = bp[0];
    float4 v;
    v.x = di * a0 + bv.x; v.y = di * a1 + bv.y;
    v.z = di * a2 + bv.z; v.w = di * a3 + bv.w;
    *reinterpret_cast<float4*>(out + (size_t)wid * 32 + 4 * l) = v;
    if (l == 0) {
        out[(size_t)NN * 32 + wid] = expf(di * (m + htm[wid]) + b2[32]);
    }
}

extern "C" void kernel_launch(void* const* d_in, const int* in_sizes, int n_in,
                              void* d_out, int out_size, void* d_ws, size_t ws_size,
                              hipStream_t stream) {
    const float* x  = (const float*)d_in[0];
    const float* W1 = (const float*)d_in[1];
    const float* b1 = (const float*)d_in[2];
    const float* W2 = (const float*)d_in[3];
    const float* b2 = (const float*)d_in[4];
    const int*   ei = (const int*)d_in[5];
    const int* src = ei;
    const int* dst = ei + NE;
    float* out = (float*)d_out;

    // workspace layout
    char* p = (char*)d_ws;
    int* gcur   = (int*)p;              p += sizeof(int) * NBUCK;
    p = (char*)(((uintptr_t)p + 255) & ~(uintptr_t)255);
    int* rs     = (int*)p;              p += sizeof(int) * NN;
    p = (char*)(((uintptr_t)p + 255) & ~(uintptr_t)255);
    int* re     = (int*)p;              p += sizeof(int) * NN;
    p = (char*)(((uintptr_t)p + 255) & ~(uintptr_t)255);
    int* csr    = (int*)p;              p += sizeof(int) * (size_t)NBUCK * CAP;
    p = (char*)(((uintptr_t)p + 255) & ~(uintptr_t)255);
    unsigned* pairs = (unsigned*)p;     p += sizeof(unsigned) * (size_t)NBUCK * CAP;
    p = (char*)(((uintptr_t)p + 255) & ~(uintptr_t)255);
    float* dinv = (float*)p;            p += sizeof(float) * NN;
    p = (char*)(((uintptr_t)p + 255) & ~(uintptr_t)255);
    float* xw   = (float*)p;            p += sizeof(float) * (size_t)NN * 64;
    p = (char*)(((uintptr_t)p + 255) & ~(uintptr_t)255);
    unsigned short* ht1 = (unsigned short*)p; p += sizeof(unsigned short) * (size_t)NN * 64;
    p = (char*)(((uintptr_t)p + 255) & ~(uintptr_t)255);
    unsigned short* htp = (unsigned short*)p; p += sizeof(unsigned short) * (size_t)NN * 32;
    p = (char*)(((uintptr_t)p + 255) & ~(uintptr_t)255);
    float* htm  = (float*)p;            p += sizeof(float) * NN;

    // ---- CSR build + gemm1 (merged, no sync needed) ----
    k_zero<<<1, 256, 0, stream>>>(gcur);
    k_split_gemm<<<NTILE + GEMM1CH, 256, 0, stream>>>(src, dst, gcur, pairs, x, W1, xw);
    k_bin2<<<NBUCK, 256, 0, stream>>>(pairs, gcur, csr, rs, re, dinv);
    k_scale<<<(NN * 8) / 256, 256, 0, stream>>>(xw, dinv, ht1);

    // ---- gather1 + fused gemm2 ----
    k_gather1<<<(NN * 8) / 256, 256, 0, stream>>>(ht1, rs, re, csr, dinv, b1, W2, htp, htm);

    // ---- layer 2 gather + epilogue ----
    k_gather2<<<(NN * 8) / 256, 256, 0, stream>>>(htp, htm, rs, re, csr, dinv, b2, out);
}

// Round 19
// 145.466 us; speedup vs baseline: 1.0557x; 1.0557x over previous
//
#include <hip/hip_runtime.h>
#include <hip/hip_bf16.h>

// GCN 2-layer: N=100000 nodes, E=1600000 edges, 64 -> 64(relu) -> 33.
// out = [pos (N*32) | mass (N*1)], float32.
//
// ht[i] = (x@W1)[i]  (UNSCALED bf16 table; per-src dinv folds into gather1's
// mask multiplier):  gcn[i] = dinv_i*(sum_e dinv_s*xw_s + dinv_i*xw_i) + b.
//
// R19 = exact R17 (best measured: 146.4us). R18's k_scale variant (+TILE=2048)
// regressed to 153.6 -> reverted. Structure:
//   k_zero | k_split_gemm (split-tiles || gemm1-chunks, merged, no sync needed)
//   | k_bin2 | k_gather1(+fused gemm2, dinv-folded) | k_gather2.

constexpr int NN = 100000;
constexpr int NE = 1600000;

constexpr int BSHIFT = 9;                               // 512 nodes per bucket
constexpr int NBUCK = (NN + (1 << BSHIFT) - 1) >> BSHIFT;   // 196
constexpr int TILE = 4096;                              // edges per split tile
constexpr int NTILE = (NE + TILE - 1) / TILE;           // 391
constexpr int GEMM1CH = (NN + 255) / 256;               // 391
constexpr int CAP = 16384;                              // bucket capacity

// ---------------- bf16 helpers ----------------

__device__ inline float bflo(unsigned w) { union { unsigned u; float f; } c; c.u = w << 16; return c.f; }
__device__ inline float bfhi(unsigned w) { union { unsigned u; float f; } c; c.u = w & 0xffff0000u; return c.f; }
__device__ inline unsigned f2bf_bits(float f) {
    __hip_bfloat16 h = __float2bfloat16(f);
    unsigned short u; __builtin_memcpy(&u, &h, 2); return (unsigned)u;
}
__device__ inline unsigned pack2(float a, float b) { return f2bf_bits(a) | (f2bf_bits(b) << 16); }

// ---------------- init: zero gcur ----------------

__global__ void k_zero(int* __restrict__ g) {
    int t = threadIdx.x;
    if (t < NBUCK) g[t] = 0;
}

// ---------------- merged split || gemm1 (no inter-block dependency) ----------------
// smem layout (split path): lcnt[256] lpre[256] gadj[200] buf[TILE] bb[TILE]
//   = 1024 + 1024 + 800 + 16384 + 4096 = 23328 B
// gemm1 path uses the first 16384 B as the W1 tile.

__global__ __launch_bounds__(256, 1) void k_split_gemm(const int* __restrict__ src,
                                                       const int* __restrict__ dst,
                                                       int* __restrict__ gcur,
                                                       unsigned* __restrict__ pairs,
                                                       const float* __restrict__ x,
                                                       const float* __restrict__ W1,
                                                       unsigned short* __restrict__ ht1) {
    __shared__ __align__(16) char smem[23552];
    int tid = threadIdx.x;

    if (blockIdx.x < NTILE) {
        // ---- split tile (exact R13 body) ----
        int* lcnt = (int*)smem;
        int* lpre = lcnt + 256;
        int* gadj = lpre + 256;
        unsigned* buf = (unsigned*)(gadj + 200);
        unsigned char* bb = (unsigned char*)(buf + TILE);
        int base = blockIdx.x * TILE;

        lcnt[tid] = 0;
        __syncthreads();

        unsigned pk[16]; short bk[16]; short lp[16];
        #pragma unroll
        for (int k = 0; k < 16; ++k) {
            int e = base + k * 256 + tid;
            bk[k] = -1;
            if (e < NE) {
                int s = src[e], d = dst[e];
                int b = d >> BSHIFT;
                pk[k] = (unsigned)s | ((unsigned)(d & ((1 << BSHIFT) - 1)) << 17);
                bk[k] = (short)b;
                lp[k] = (short)atomicAdd(&lcnt[b], 1);
            }
        }
        __syncthreads();

        lpre[tid] = lcnt[tid];
        __syncthreads();
        for (int off = 1; off < 256; off <<= 1) {
            int v = (tid >= off) ? lpre[tid - off] : 0;
            __syncthreads();
            lpre[tid] += v;
            __syncthreads();
        }
        int total = lpre[255];

        if (tid < NBUCK) {
            int ex = lpre[tid] - lcnt[tid];
            gadj[tid] = tid * CAP + atomicAdd(&gcur[tid], lcnt[tid]) - ex;
        }
        __syncthreads();

        #pragma unroll
        for (int k = 0; k < 16; ++k) {
            if (bk[k] >= 0) {
                int b = bk[k];
                int i = (lpre[b] - lcnt[b]) + lp[k];
                buf[i] = pk[k];
                bb[i] = (unsigned char)b;
            }
        }
        __syncthreads();

        for (int i = tid; i < total; i += 256) {
            pairs[gadj[bb[i]] + i] = buf[i];
        }
    } else {
        // ---- gemm1 chunk (UNSCALED output) ----
        float* w = (float*)smem;
        for (int t = tid; t < 64 * 64; t += 256) w[t] = W1[t];
        __syncthreads();

        int i = (blockIdx.x - NTILE) * 256 + tid;
        if (i >= NN) return;

        float acc[64];
        #pragma unroll
        for (int f = 0; f < 64; ++f) acc[f] = 0.f;

        const float4* xp = reinterpret_cast<const float4*>(x + (size_t)i * 64);
        #pragma unroll
        for (int kc = 0; kc < 4; ++kc) {
            float4 c0 = xp[4 * kc + 0], c1 = xp[4 * kc + 1];
            float4 c2 = xp[4 * kc + 2], c3 = xp[4 * kc + 3];
            float xs[16] = {c0.x, c0.y, c0.z, c0.w, c1.x, c1.y, c1.z, c1.w,
                            c2.x, c2.y, c2.z, c2.w, c3.x, c3.y, c3.z, c3.w};
            #pragma unroll
            for (int kk = 0; kk < 16; ++kk) {
                float xk = xs[kk];
                const float4* wr = reinterpret_cast<const float4*>(w + (16 * kc + kk) * 64);
                #pragma unroll
                for (int f4 = 0; f4 < 16; ++f4) {
                    float4 wv = wr[f4];
                    acc[4 * f4 + 0] += xk * wv.x;
                    acc[4 * f4 + 1] += xk * wv.y;
                    acc[4 * f4 + 2] += xk * wv.z;
                    acc[4 * f4 + 3] += xk * wv.w;
                }
            }
        }

        uint4* hp = reinterpret_cast<uint4*>(ht1 + (size_t)i * 64);
        #pragma unroll
        for (int q = 0; q < 8; ++q) {
            uint4 v;
            v.x = pack2(acc[8 * q + 0], acc[8 * q + 1]);
            v.y = pack2(acc[8 * q + 2], acc[8 * q + 3]);
            v.z = pack2(acc[8 * q + 4], acc[8 * q + 5]);
            v.w = pack2(acc[8 * q + 6], acc[8 * q + 7]);
            hp[q] = v;
        }
    }
}

// ---------------- pass 2: block-per-bucket; emits csr (padded), rs, re, dinv ----------------

__global__ __launch_bounds__(256) void k_bin2(const unsigned* __restrict__ pairs,
                                              const int* __restrict__ gcur,
                                              int* __restrict__ csr,
                                              int* __restrict__ rs,
                                              int* __restrict__ re,
                                              float* __restrict__ dinv) {
    int b = blockIdx.x;
    int lo = b << BSHIFT;
    int nn = min(1 << BSHIFT, NN - lo);
    int t = threadIdx.x;
    int beg = b * CAP;
    int endd = beg + gcur[b];

    __shared__ int lcnt[1 << BSHIFT];
    __shared__ int loff[1 << BSHIFT];
    __shared__ int wsum[256];

    for (int i = t; i < (1 << BSHIFT); i += 256) lcnt[i] = 0;
    __syncthreads();
    for (int idx = beg + t; idx < endd; idx += 256)
        atomicAdd(&lcnt[pairs[idx] >> 17], 1);
    __syncthreads();

    int v0 = lcnt[2 * t], v1 = lcnt[2 * t + 1];
    int s = v0 + v1;
    wsum[t] = s; __syncthreads();
    for (int off = 1; off < 256; off <<= 1) {
        int a = (t >= off) ? wsum[t - off] : 0;
        __syncthreads();
        wsum[t] += a;
        __syncthreads();
    }
    int ex = wsum[t] - s;
    loff[2 * t] = ex; loff[2 * t + 1] = ex + v0;
    __syncthreads();

    for (int i = t; i < nn; i += 256) {
        int st = beg + loff[i];
        rs[lo + i] = st;
        re[lo + i] = st + lcnt[i];
        dinv[lo + i] = rsqrtf((float)lcnt[i] + 1.0f);
    }
    __syncthreads();
    for (int i = t; i < (1 << BSHIFT); i += 256) lcnt[i] = 0;  // reuse as cursors
    __syncthreads();

    for (int idx = beg + t; idx < endd; idx += 256) {
        unsigned v = pairs[idx];
        int dl = (int)(v >> 17);
        int p = atomicAdd(&lcnt[dl], 1);
        csr[beg + loff[dl] + p] = (int)(v & 0x1FFFFu);
    }
}

// ---------------- gather1 + relu + fused gemm2 (LDS-staged) -> htp, htm ----------------
// grid = NN*8/256 = 3125 exact; 8 lanes/node; 32 nodes/block. Per-edge dinv fold.

__global__ __launch_bounds__(256) void k_gather1(const unsigned short* __restrict__ ht,
                                                 const int* __restrict__ rs,
                                                 const int* __restrict__ re,
                                                 const int* __restrict__ csr,
                                                 const float* __restrict__ dinv,
                                                 const float* __restrict__ b1,
                                                 const float* __restrict__ W2,
                                                 unsigned short* __restrict__ htp,
                                                 float* __restrict__ htm) {
    __shared__ float w2s[64 * 36];     // W2 padded to stride 36
    __shared__ float hs[32 * 68];      // 32 h rows, stride 68 (bank-spread)

    for (int t = threadIdx.x; t < 64 * 36; t += 256) {
        int k = t / 36, c = t - k * 36;
        w2s[t] = (c < 33) ? W2[k * 33 + c] : 0.f;
    }

    int wid = (blockIdx.x * 256 + threadIdx.x) >> 3;
    int g = threadIdx.x >> 3;          // group (node slot) in block: 0..31
    int l = threadIdx.x & 7;           // lane in group: feats 8l..8l+7
    int beg = rs[wid], end = re[wid];

    float av[8];
    #pragma unroll
    for (int k = 0; k < 8; ++k) av[k] = 0.f;

    for (int j0 = beg; j0 < end; j0 += 8) {
        int jj = j0 + l;
        int sv = csr[min(jj, end - 1)];
        float dvl = dinv[sv];
        uint4 rows[8]; float ds[8];
        #pragma unroll
        for (int e = 0; e < 8; ++e) {
            int s = __shfl(sv, e, 8);
            ds[e] = __shfl(dvl, e, 8);
            rows[e] = *reinterpret_cast<const uint4*>(ht + (size_t)s * 64 + 8 * l);
        }
        #pragma unroll
        for (int e = 0; e < 8; ++e) {
            float msk = (j0 + e < end) ? ds[e] : 0.f;
            uint4 w = rows[e];
            av[0] += msk * bflo(w.x); av[1] += msk * bfhi(w.x);
            av[2] += msk * bflo(w.y); av[3] += msk * bfhi(w.y);
            av[4] += msk * bflo(w.z); av[5] += msk * bfhi(w.z);
            av[6] += msk * bflo(w.w); av[7] += msk * bfhi(w.w);
        }
    }

    // self term (scaled by own dinv) + relu epilogue -> h row staged to LDS
    float di = dinv[wid];
    uint4 sw = *reinterpret_cast<const uint4*>(ht + (size_t)wid * 64 + 8 * l);
    av[0] += di * bflo(sw.x); av[1] += di * bfhi(sw.x);
    av[2] += di * bflo(sw.y); av[3] += di * bfhi(sw.y);
    av[4] += di * bflo(sw.z); av[5] += di * bfhi(sw.z);
    av[6] += di * bflo(sw.w); av[7] += di * bfhi(sw.w);

    const float4* bp = reinterpret_cast<const float4*>(b1 + 8 * l);
    float4 bA = bp[0], bB = bp[1];
    float4 vA, vB;
    vA.x = fmaxf(di * av[0] + bA.x, 0.f); vA.y = fmaxf(di * av[1] + bA.y, 0.f);
    vA.z = fmaxf(di * av[2] + bA.z, 0.f); vA.w = fmaxf(di * av[3] + bA.w, 0.f);
    vB.x = fmaxf(di * av[4] + bB.x, 0.f); vB.y = fmaxf(di * av[5] + bB.y, 0.f);
    vB.z = fmaxf(di * av[6] + bB.z, 0.f); vB.w = fmaxf(di * av[7] + bB.w, 0.f);
    float* hp = hs + g * 68 + 8 * l;
    *reinterpret_cast<float4*>(hp)     = vA;
    *reinterpret_cast<float4*>(hp + 4) = vB;
    __syncthreads();

    // fused gemm2: thread computes its node's cols 4l..4l+3 (+ col 32 broadcast)
    float acc0 = 0.f, acc1 = 0.f, acc2 = 0.f, acc3 = 0.f, accm = 0.f;
    const float* hrow = hs + g * 68;
    #pragma unroll 8
    for (int k = 0; k < 64; ++k) {
        float hv = hrow[k];
        const float* wr = w2s + k * 36 + 4 * l;
        acc0 += hv * wr[0];
        acc1 += hv * wr[1];
        acc2 += hv * wr[2];
        acc3 += hv * wr[3];
        accm += hv * w2s[k * 36 + 32];   // wave-uniform broadcast
    }
    uint2 pv;
    pv.x = pack2(acc0 * di, acc1 * di);
    pv.y = pack2(acc2 * di, acc3 * di);
    *reinterpret_cast<uint2*>(htp + (size_t)wid * 32 + 4 * l) = pv;
    if (l == 0) htm[wid] = accm * di;
}

// ---------------- layer 2 gather: 8 lanes/node, lane owns 4 cols; mass 3-shfl ----------------

__global__ __launch_bounds__(256) void k_gather2(const unsigned short* __restrict__ htp,
                                                 const float* __restrict__ htm,
                                                 const int* __restrict__ rs,
                                                 const int* __restrict__ re,
                                                 const int* __restrict__ csr,
                                                 const float* __restrict__ dinv,
                                                 const float* __restrict__ b2,
                                                 float* __restrict__ out) {
    int wid = (blockIdx.x * 256 + threadIdx.x) >> 3;
    int l = threadIdx.x & 7;           // lane in group: cols 4l..4l+3
    int beg = rs[wid], end = re[wid];

    float a0 = 0.f, a1 = 0.f, a2 = 0.f, a3 = 0.f, m = 0.f;
    for (int j0 = beg; j0 < end; j0 += 8) {
        int jj = j0 + l;
        int sv = csr[min(jj, end - 1)];
        if (jj < end) m += htm[sv];    // lane's own edge's mass
        uint2 rows[8];
        #pragma unroll
        for (int e = 0; e < 8; ++e) {
            int s = __shfl(sv, e, 8);
            rows[e] = *reinterpret_cast<const uint2*>(htp + (size_t)s * 32 + 4 * l);
        }
        #pragma unroll
        for (int e = 0; e < 8; ++e) {
            float msk = (j0 + e < end) ? 1.f : 0.f;
            uint2 w = rows[e];
            a0 += msk * bflo(w.x); a1 += msk * bfhi(w.x);
            a2 += msk * bflo(w.y); a3 += msk * bfhi(w.y);
        }
    }

    // mass reduce across the 8-lane group only
    m += __shfl_xor(m, 1); m += __shfl_xor(m, 2); m += __shfl_xor(m, 4);

    float di = dinv[wid];
    uint2 sw = *reinterpret_cast<const uint2*>(htp + (size_t)wid * 32 + 4 * l);
    a0 += bflo(sw.x); a1 += bfhi(sw.x); a2 += bflo(sw.y); a3 += bfhi(sw.y);
    const float4* bp = reinterpret_cast<const float4*>(b2 + 4 * l);
    float4 bv = bp[0];
    float4 v;
    v.x = di * a0 + bv.x; v.y = di * a1 + bv.y;
    v.z = di * a2 + bv.z; v.w = di * a3 + bv.w;
    *reinterpret_cast<float4*>(out + (size_t)wid * 32 + 4 * l) = v;
    if (l == 0) {
        out[(size_t)NN * 32 + wid] = expf(di * (m + htm[wid]) + b2[32]);
    }
}

extern "C" void kernel_launch(void* const* d_in, const int* in_sizes, int n_in,
                              void* d_out, int out_size, void* d_ws, size_t ws_size,
                              hipStream_t stream) {
    const float* x  = (const float*)d_in[0];
    const float* W1 = (const float*)d_in[1];
    const float* b1 = (const float*)d_in[2];
    const float* W2 = (const float*)d_in[3];
    const float* b2 = (const float*)d_in[4];
    const int*   ei = (const int*)d_in[5];
    const int* src = ei;
    const int* dst = ei + NE;
    float* out = (float*)d_out;

    // workspace layout
    char* p = (char*)d_ws;
    int* gcur   = (int*)p;              p += sizeof(int) * NBUCK;
    p = (char*)(((uintptr_t)p + 255) & ~(uintptr_t)255);
    int* rs     = (int*)p;              p += sizeof(int) * NN;
    p = (char*)(((uintptr_t)p + 255) & ~(uintptr_t)255);
    int* re     = (int*)p;              p += sizeof(int) * NN;
    p = (char*)(((uintptr_t)p + 255) & ~(uintptr_t)255);
    int* csr    = (int*)p;              p += sizeof(int) * (size_t)NBUCK * CAP;
    p = (char*)(((uintptr_t)p + 255) & ~(uintptr_t)255);
    unsigned* pairs = (unsigned*)p;     p += sizeof(unsigned) * (size_t)NBUCK * CAP;
    p = (char*)(((uintptr_t)p + 255) & ~(uintptr_t)255);
    float* dinv = (float*)p;            p += sizeof(float) * NN;
    p = (char*)(((uintptr_t)p + 255) & ~(uintptr_t)255);
    unsigned short* ht1 = (unsigned short*)p; p += sizeof(unsigned short) * (size_t)NN * 64;
    p = (char*)(((uintptr_t)p + 255) & ~(uintptr_t)255);
    unsigned short* htp = (unsigned short*)p; p += sizeof(unsigned short) * (size_t)NN * 32;
    p = (char*)(((uintptr_t)p + 255) & ~(uintptr_t)255);
    float* htm  = (float*)p;            p += sizeof(float) * NN;

    // ---- CSR build + gemm1 (merged, no sync needed) ----
    k_zero<<<1, 256, 0, stream>>>(gcur);
    k_split_gemm<<<NTILE + GEMM1CH, 256, 0, stream>>>(src, dst, gcur, pairs, x, W1, ht1);
    k_bin2<<<NBUCK, 256, 0, stream>>>(pairs, gcur, csr, rs, re, dinv);

    // ---- gather1 + fused gemm2 ----
    k_gather1<<<(NN * 8) / 256, 256, 0, stream>>>(ht1, rs, re, csr, dinv, b1, W2, htp, htm);

    // ---- layer 2 gather + epilogue ----
    k_gather2<<<(NN * 8) / 256, 256, 0, stream>>>(htp, htm, rs, re, csr, dinv, b2, out);
}